// Round 7
// baseline (415.152 us; speedup 1.0000x reference)
//
#include <hip/hip_runtime.h>
#include <hip/hip_fp16.h>
#include <math.h>

#define H 1024
#define V 18
#define NUM_NODES 7
#define LEN 40
#define BATCH 512
#define NWG 256
#define NT 1024

#define AGENT __HIP_MEMORY_SCOPE_AGENT
typedef unsigned long long u64;
typedef _Float16 half2v __attribute__((ext_vector_type(2)));

// slot = (tag<<32) | (2 x f16 payload), padded to 128B (16 u64)
#define SLOTS 512
#define SSTR 16
// ws layout (u64 units):
//   h1s [2][512][16]  (128 KB)
//   h2s [2][512][16]  (128 KB)
//   then c1buf[1024] f32, c2buf[1024] f32 (8 KB)
#define WS_ZERO_U32 (2 * 2 * SLOTS * SSTR * 2 + 2048)

__device__ __forceinline__ float wred(float v) {
#pragma unroll
  for (int off = 32; off > 0; off >>= 1) v += __shfl_xor(v, off, 64);
  return v;
}
__device__ __forceinline__ float sigm(float x) { return 1.0f / (1.0f + expf(-x)); }
__device__ __forceinline__ float dot4(float4 a, float4 b) {
  return a.x * b.x + a.y * b.y + a.z * b.z + a.w * b.w;
}

__device__ __forceinline__ float fdot2_(unsigned w, unsigned h, float c) {
  half2v a = __builtin_bit_cast(half2v, w);
  half2v b = __builtin_bit_cast(half2v, h);
#if __has_builtin(__builtin_amdgcn_fdot2)
  return __builtin_amdgcn_fdot2(a, b, c, false);
#else
  return c + (float)a.x * (float)b.x + (float)a.y * (float)b.y;
#endif
}

// dot of one 1024-elem f16 row (LDS) with f16-packed h vector (LDS), fp32 accum.
__device__ __forceinline__ float dot_row(const unsigned* wrow, const unsigned* hp, int lane) {
  float a = 0.f;
#pragma unroll
  for (int k = 0; k < 4; ++k) {
    uint2 w = *(const uint2*)(wrow + 2 * lane + 128 * k);
    uint2 h = *(const uint2*)(hp + 2 * lane + 128 * k);
    a = fdot2_(w.x, h.x, a);
    a = fdot2_(w.y, h.y, a);
  }
  return a;
}

__global__ void __launch_bounds__(256) init_ws_kernel(unsigned* p, int n) {
  int i = blockIdx.x * 256 + threadIdx.x;
  if (i < n) p[i] = 0u;
}

__global__ void __launch_bounds__(NT, 4) decoder_kernel(
    const int* __restrict__ x0,
    const float* __restrict__ emb,    // [V][H]
    const float* __restrict__ w_ih,   // [L][4H][H]
    const float* __restrict__ w_hh,   // [L][4H][H]
    const float* __restrict__ b_ih,   // [L][4H]
    const float* __restrict__ b_hh,   // [L][4H]
    const float* __restrict__ w_fc,   // [V][H]
    const float* __restrict__ b_fc,   // [V]
    float* __restrict__ out,
    float* __restrict__ ws)
{
  u64* h1s = (u64*)ws;                         // [2][512][16]
  u64* h2s = h1s + 2 * SLOTS * SSTR;           // [2][512][16]
  float* c1buf = (float*)(h2s + 2 * SLOTS * SSTR);
  float* c2buf = c1buf + H;

  float* out_tok  = out;                           // [LEN][BATCH] (as float)
  float* out_outs = out + LEN * BATCH;             // [BATCH][V]
  float* out_hf   = out_outs + BATCH * V;          // [2][BATCH][H]
  float* out_cf   = out_hf + 2 * BATCH * H;        // [2][BATCH][H]

  const int wg = blockIdx.x, tid = threadIdx.x;
  const int wave = tid >> 6, lane = tid & 63;
  const int q = wave & 3;                // gate (i,f,g,o)
  const int u = wave >> 2;               // unit-within-WG (0..3)
  const int row = q * H + (wg * 4 + u);  // gate row within a layer

  // ---- LDS-resident f16 weights ----
  // slots: 0..15 wh0[wave], 16..31 wi1[wave], 32..47 wh1[wave], 48..65 wfc[v]
  __shared__ unsigned wlds[66][512];       // 132 KB
  __shared__ unsigned h1p[SLOTS], h2p[SLOTS];  // f16-packed h vectors (2 per u32)
  __shared__ float s_eix[16][V];
  __shared__ float s_g1[4][4], s_g2[4][4];
  __shared__ float s_logits[V];
  __shared__ float s_bfc[V];

  // ---- prologue 1: stage weights (fp32 global -> f16 LDS) ----
  for (int i = tid; i < 66 * 512; i += NT) {
    const int slot = i >> 9, p = i & 511;
    const float* src;
    if (slot < 16) {
      src = w_hh + (size_t)((slot & 3) * H + wg * 4 + (slot >> 2)) * H;
    } else if (slot < 32) {
      const int s = slot - 16;
      src = w_ih + (size_t)(4 * H + (s & 3) * H + wg * 4 + (s >> 2)) * H;
    } else if (slot < 48) {
      const int s = slot - 32;
      src = w_hh + (size_t)(4 * H + (s & 3) * H + wg * 4 + (s >> 2)) * H;
    } else {
      src = w_fc + (size_t)(slot - 48) * H;
    }
    float2 f = *(const float2*)(src + 2 * p);
    __half2 hh = __floats2half2_rn(f.x, f.y);
    wlds[slot][p] = *(unsigned*)&hh;
  }
  if (tid < V) s_bfc[tid] = b_fc[tid];
  if (tid < SLOTS) { h1p[tid] = 0u; h2p[tid] = 0u; }

  // ---- prologue 2: eix[wave][v] = wi0_row . emb[v] + b0 (fp32, emb const) ----
  {
    float4 wi0[4];
    const float4* p0p = (const float4*)(w_ih + (size_t)row * H);
#pragma unroll
    for (int m = 0; m < 4; ++m) wi0[m] = p0p[lane + 64 * m];
    const float bsum0 = b_ih[row] + b_hh[row];
    for (int v = 0; v < V; ++v) {
      const float4* er = (const float4*)(emb + (size_t)v * H);
      float a = 0.f;
#pragma unroll
      for (int m = 0; m < 4; ++m) a += dot4(wi0[m], er[lane + 64 * m]);
      a = wred(a);
      if (lane == 0) s_eix[wave][v] = a + bsum0;
    }
  }
  const float bsum1 = b_ih[4 * H + row] + b_hh[4 * H + row];
  __syncthreads();

  int tok = x0[0];
  float p0 = 0.f;            // wh0 . h1(t-1), precomputed previous step
  float c1 = 0.f, c2 = 0.f;  // cell states (wave0 lanes 0..3)

  for (int t = 0; t < LEN; ++t) {
    const int pw = t & 1;
    const unsigned tag = (unsigned)(t + 1);

    // ---- Phase A: layer-0 gates = eix[tok] + p0 ----
    {
      float g0 = wred(p0);
      if (lane == 0) s_g1[u][q] = g0 + s_eix[wave][tok];
    }
    __syncthreads();
    // producers: wave 0 lanes 0..3 compute h1 units, publish f16 pairs
    if (wave == 0 && lane < 4) {
      float ig = sigm(s_g1[lane][0]), fg = sigm(s_g1[lane][1]);
      float gg = tanhf(s_g1[lane][2]), og = sigm(s_g1[lane][3]);
      c1 = fg * c1 + ig * gg;
      float hn = og * tanhf(c1);
      if (t == LEN - 1) {
        __hip_atomic_store(&c1buf[wg * 4 + lane], c1, __ATOMIC_RELAXED, AGENT);
        asm volatile("s_waitcnt vmcnt(0)" ::: "memory");
      }
      float hx = __shfl_down(hn, 1);     // lanes 0,2 pick up neighbor
      if ((lane & 1) == 0) {
        __half2 hh = __floats2half2_rn(hn, hx);
        u64 x = ((u64)tag << 32) | (u64)(*(unsigned*)&hh);
        __hip_atomic_store(&h1s[(size_t)(pw * SLOTS + wg * 2 + (lane >> 1)) * SSTR],
                           x, __ATOMIC_RELAXED, AGENT);
      }
    }
    // all waves: overlap with sync — wh1 . h2(t-1)
    float p1 = dot_row(wlds[32 + wave], h2p, lane);
    // pollers: waves 8..15, one slot each
    if (tid >= 512) {
      const int s = tid - 512;
      u64* slot = &h1s[(size_t)(pw * SLOTS + s) * SSTR];
      u64 x;
      for (;;) {
        x = __hip_atomic_load(slot, __ATOMIC_RELAXED, AGENT);
        if ((unsigned)(x >> 32) == tag) break;
        __builtin_amdgcn_s_sleep(1);
      }
      h1p[s] = (unsigned)x;
    }
    __syncthreads();

    // ---- Phase B: layer-1 gates = p1 + wi1 . h1(t) ----
    {
      float a = p1 + dot_row(wlds[16 + wave], h1p, lane);
      a = wred(a);
      if (lane == 0) s_g2[u][q] = a + bsum1;
    }
    __syncthreads();
    if (wave == 0 && lane < 4) {
      float ig = sigm(s_g2[lane][0]), fg = sigm(s_g2[lane][1]);
      float gg = tanhf(s_g2[lane][2]), og = sigm(s_g2[lane][3]);
      c2 = fg * c2 + ig * gg;
      float hn = og * tanhf(c2);
      if (t == LEN - 1) {
        __hip_atomic_store(&c2buf[wg * 4 + lane], c2, __ATOMIC_RELAXED, AGENT);
        asm volatile("s_waitcnt vmcnt(0)" ::: "memory");
      }
      float hx = __shfl_down(hn, 1);
      if ((lane & 1) == 0) {
        __half2 hh = __floats2half2_rn(hn, hx);
        u64 x = ((u64)tag << 32) | (u64)(*(unsigned*)&hh);
        __hip_atomic_store(&h2s[(size_t)(pw * SLOTS + wg * 2 + (lane >> 1)) * SSTR],
                           x, __ATOMIC_RELAXED, AGENT);
      }
    }
    // all waves: overlap — next step's wh0 . h1(t)
    float p0n = dot_row(wlds[wave], h1p, lane);
    if (tid >= 512) {
      const int s = tid - 512;
      u64* slot = &h2s[(size_t)(pw * SLOTS + s) * SSTR];
      u64 x;
      for (;;) {
        x = __hip_atomic_load(slot, __ATOMIC_RELAXED, AGENT);
        if ((unsigned)(x >> 32) == tag) break;
        __builtin_amdgcn_s_sleep(1);
      }
      h2p[s] = (unsigned)x;
    }
    __syncthreads();
    p0 = p0n;

    // ---- Phase C: fc + argmax (redundant per WG, local only) ----
    {
      float a = dot_row(wlds[48 + wave], h2p, lane);
      a = wred(a);
      if (lane == 0) s_logits[wave] = a + s_bfc[wave];
      if (wave >= 14) {  // waves 14,15 also cover v = 16,17
        float a2 = dot_row(wlds[48 + wave + 2], h2p, lane);
        a2 = wred(a2);
        if (lane == 0) s_logits[wave + 2] = a2 + s_bfc[wave + 2];
      }
      __syncthreads();
      // every thread: local argmax (no broadcast sync needed)
      {
        const int node_end = ((t >> 1) % 10) / 2 + 3;
        float bv = -INFINITY;
        int bi = 0;
        for (int v = 0; v < V; ++v) {
          bool m = (t & 1) ? (v >= NUM_NODES) : (v >= 1 && v < node_end);
          if (m && s_logits[v] > bv) { bv = s_logits[v]; bi = v; }
        }
        tok = bi;
      }
      if (wg == 0) {
        if (tid < BATCH) out_tok[t * BATCH + tid] = (float)tok;
        if (t == LEN - 1) {
          float mx = -INFINITY;
          for (int v = 0; v < V; ++v) mx = fmaxf(mx, s_logits[v]);
          float s = 0.f;
          for (int v = 0; v < V; ++v) s += expf(s_logits[v] - mx);
          const float lse = mx + logf(s);
          for (int i = tid; i < BATCH * V; i += NT)
            out_outs[i] = s_logits[i % V] - lse;
        }
      }
    }
  }

  // ---- Final outputs: h_f from f16 staged vectors, c_f from global bufs ----
  {
    const unsigned u1 = h1p[tid >> 1], u2 = h2p[tid >> 1];
    const half2v v1 = __builtin_bit_cast(half2v, u1);
    const half2v v2 = __builtin_bit_cast(half2v, u2);
    const float h1v = (float)((tid & 1) ? v1.y : v1.x);
    const float h2v = (float)((tid & 1) ? v2.y : v2.x);
    const float cv1 = __hip_atomic_load(&c1buf[tid], __ATOMIC_RELAXED, AGENT);
    const float cv2 = __hip_atomic_load(&c2buf[tid], __ATOMIC_RELAXED, AGENT);
#pragma unroll
    for (int rr = 0; rr < 4; ++rr) {
      const int r = wg + rr * NWG;      // row in [0, 1024)
      const int l = r >> 9;             // layer
      out_hf[(size_t)r * H + tid] = l ? h2v : h1v;
      out_cf[(size_t)r * H + tid] = l ? cv2 : cv1;
    }
  }
}

extern "C" void kernel_launch(void* const* d_in, const int* in_sizes, int n_in,
                              void* d_out, int out_size, void* d_ws, size_t ws_size,
                              hipStream_t stream) {
  const int*   x0   = (const int*)d_in[0];
  const float* emb  = (const float*)d_in[1];
  const float* w_ih = (const float*)d_in[2];
  const float* w_hh = (const float*)d_in[3];
  const float* b_ih = (const float*)d_in[4];
  const float* b_hh = (const float*)d_in[5];
  const float* w_fc = (const float*)d_in[6];
  const float* b_fc = (const float*)d_in[7];
  float* ws = (float*)d_ws;

  hipLaunchKernelGGL(init_ws_kernel, dim3((WS_ZERO_U32 + 255) / 256), dim3(256), 0, stream,
                     (unsigned*)ws, WS_ZERO_U32);
  hipLaunchKernelGGL(decoder_kernel, dim3(NWG), dim3(NT), 0, stream,
                     x0, emb, w_ih, w_hh, b_ih, b_hh, w_fc, b_fc,
                     (float*)d_out, ws);
}